// Round 2
// baseline (692.841 us; speedup 1.0000x reference)
//
#include <hip/hip_runtime.h>

#define NC 32
#define NVOX (96*96*96)
#define NB 384            // blocks per sample: 384*256*9 == NVOX exactly
#define TPB 256

// workspace layout (floats), per-sample stride
#define WS_CE     0
#define WS_SP     32
#define WS_SPT    64
#define WS_SINKI  96
#define WS_SIB    100
#define WS_TGT    104
#define WS_HIST   128
#define WS_STRIDE 1280

__device__ __forceinline__ float wave_reduce(float v) {
    #pragma unroll
    for (int off = 32; off > 0; off >>= 1)
        v += __shfl_down(v, off, 64);
    return v;
}

__global__ __launch_bounds__(TPB) void voxel_kernel(
    const float* __restrict__ images,
    const int*   __restrict__ targets,
    const int*   __restrict__ masks,     // bools promoted to 4-byte on device
    float* __restrict__ ws,
    float* __restrict__ pred_out)
{
    const int b   = blockIdx.x & 1;     // interleave samples across XCDs
    const int blk = blockIdx.x >> 1;
    const int tid = threadIdx.x;

    __shared__ float s_hist[NC * NC];
    __shared__ float s_spt[NC];
    __shared__ float s_mf[NC];

    for (int i = tid; i < NC * NC; i += TPB) s_hist[i] = 0.f;
    if (tid < NC) {
        s_spt[tid] = 0.f;
        s_mf[tid]  = (masks[b * NC + tid] != 0) ? 1.f : 0.f;
    }
    __syncthreads();

    const float* img  = images + (size_t)b * NC * NVOX;
    const int*   tgt  = targets + (size_t)b * NVOX;
    float*       pout = pred_out + (size_t)b * NVOX;
    float*       wsb  = ws + (size_t)b * WS_STRIDE;

    float sp[NC];
    #pragma unroll
    for (int c = 0; c < NC; ++c) sp[c] = 0.f;
    float ce = 0.f;
    float sinkI[4] = {0.f, 0.f, 0.f, 0.f};
    float sibc[4]  = {0.f, 0.f, 0.f, 0.f};
    float tgtc[4]  = {0.f, 0.f, 0.f, 0.f};

    for (int v = blk * TPB + tid; v < NVOX; v += NB * TPB) {
        const int  y     = tgt[v];
        const bool valid = (y != 255);
        const int  ysafe = valid ? y : 0;
        const float vwf  = valid ? 1.f : 0.f;

        // load 32 channels; argmax over RAW x for leaves (first-max, strict >)
        float e[NC];
        float sum  = 0.f;
        float best = -3.4e38f;
        int   pred = 4;
        #pragma unroll
        for (int c = 0; c < NC; ++c) {
            float x  = img[(size_t)c * NVOX + v];
            float ev = __expf(x);
            e[c] = ev;
            sum += ev;
            if (c >= 4 && x > best) { best = x; pred = c; }
        }
        const float rinv = 1.f / sum;
        pout[v] = (float)pred;

        const int pp = (pred - 4) / 7;                      // parent of pred, 0..3
        const int py = (ysafe >= 4) ? (ysafe - 4) / 7 : -1; // parent of y or -1

        // per-class prob sums + select p[y], p[parent(y)]
        float pyv = 0.f, ppv = 0.f;
        #pragma unroll
        for (int c = 0; c < NC; ++c) {
            float pc = e[c] * rinv;
            sp[c] += pc * vwf;
            if (c == ysafe) pyv = pc;
            if (c == py)    ppv = pc;
        }

        // CE: -(logp[y]*mf[y] + logp[py]*mf[py]) * vw   (t = ancestors-or-self of y)
        float term = __logf(fminf(fmaxf(pyv, 1e-7f), 1.f - 1e-7f)) * s_mf[ysafe];
        if (py >= 0)
            term += __logf(fminf(fmaxf(ppv, 1e-7f), 1.f - 1e-7f)) * s_mf[py];
        ce -= term * vwf;

        // dice intersection terms (inter[c] = sum over voxels with y in D(c) of p[c])
        atomicAdd(&s_spt[ysafe], pyv * vwf);
        if (py >= 0) atomicAdd(&s_spt[py], ppv * vwf);

        // joint histogram hist[pred, y]
        atomicAdd(&s_hist[pred * NC + ysafe], vwf);

        // sink accounting (exactly one k==pp gets tgt; sib can hit k==py too)
        const bool predMasked = (s_mf[pred] == 0.f);
        #pragma unroll
        for (int k = 0; k < 4; ++k) {
            const int  sk   = 4 + 7 * k;
            const bool ysib = (py == k) && (ysafe != sk);
            const bool msib = predMasked && (pp == k) && (pred != sk);
            const bool sib  = ysib || msib;
            if (sib && valid) sibc[k] += 1.f;
            const bool tg = (pp == k) && !sib && valid;
            if (tg) {
                tgtc[k]  += 1.f;
                sinkI[k] += e[sk] * rinv;
            }
        }
    }

    // wave reduce register accumulators, lane0 -> global atomics
    const int lane = tid & 63;
    #pragma unroll
    for (int c = 0; c < NC; ++c) {
        float r = wave_reduce(sp[c]);
        if (lane == 0) atomicAdd(&wsb[WS_SP + c], r);
    }
    {
        float r = wave_reduce(ce);
        if (lane == 0) atomicAdd(&wsb[WS_CE], r);
    }
    #pragma unroll
    for (int k = 0; k < 4; ++k) {
        float r = wave_reduce(sinkI[k]);
        if (lane == 0) atomicAdd(&wsb[WS_SINKI + k], r);
        r = wave_reduce(sibc[k]);
        if (lane == 0) atomicAdd(&wsb[WS_SIB + k], r);
        r = wave_reduce(tgtc[k]);
        if (lane == 0) atomicAdd(&wsb[WS_TGT + k], r);
    }

    __syncthreads();
    for (int i = tid; i < NC * NC; i += TPB) {
        float h = s_hist[i];
        if (h != 0.f) atomicAdd(&wsb[WS_HIST + i], h);
    }
    if (tid < NC) {
        float v2 = s_spt[tid];
        if (v2 != 0.f) atomicAdd(&wsb[WS_SPT + tid], v2);
    }
}

__global__ __launch_bounds__(64) void finalize_kernel(
    const float* __restrict__ ws,
    const int*   __restrict__ masks,
    float* __restrict__ out)
{
    const int b = blockIdx.x;
    const float* wsb  = ws + (size_t)b * WS_STRIDE;
    const float* hist = wsb + WS_HIST;
    const int tid = threadIdx.x;

    __shared__ float s_col[NC], s_row[NC], s_dice[NC], s_mf[NC];

    if (tid < NC) {
        float cs = 0.f, rs = 0.f;
        for (int j = 0; j < NC; ++j) {
            cs += hist[j * NC + tid];
            rs += hist[tid * NC + j];
        }
        s_col[tid] = cs;
        s_row[tid] = rs;
        s_mf[tid]  = (masks[b * NC + tid] != 0) ? 1.f : 0.f;
    }
    __syncthreads();

    if (tid < NC) {
        const int c = tid;
        float ycnt, pcnt, tp;
        if (c < 4) {
            int idx[8];
            idx[0] = c;
            for (int j = 0; j < 7; ++j) idx[1 + j] = 4 + 7 * c + j;
            ycnt = s_col[c]; pcnt = s_row[c];
            for (int j = 0; j < 7; ++j) { ycnt += s_col[idx[1 + j]]; pcnt += s_row[idx[1 + j]]; }
            tp = 0.f;
            for (int a = 0; a < 8; ++a)
                for (int d = 0; d < 8; ++d)
                    tp += hist[idx[a] * NC + idx[d]];
        } else {
            ycnt = s_col[c]; pcnt = s_row[c];
            tp = hist[c * NC + c];
        }
        const float mf = s_mf[c];
        out[6 + (b * NC + c) * 3 + 0] = tp * mf;
        out[6 + (b * NC + c) * 3 + 1] = (pcnt - tp) * mf;
        out[6 + (b * NC + c) * 3 + 2] = (ycnt - tp) * mf;
        float dc = 1.f - 2.f * wsb[WS_SPT + c] / (wsb[WS_SP + c] + ycnt + 1e-5f);
        s_dice[c] = dc * mf;
    }
    __syncthreads();

    if (tid == 0) {
        float vw = 0.f, dsum = 0.f, msum = 0.f;
        for (int c = 0; c < NC; ++c) {
            vw   += s_col[c];
            dsum += s_dice[c];
            msum += s_mf[c];
        }
        const float ce   = wsb[WS_CE] / fmaxf(vw, 1.f);
        const float dice = dsum / fmaxf(msum, 1.f);
        float cnt = 0.f, sd = 0.f;
        for (int k = 0; k < 4; ++k) {
            float fl = (wsb[WS_SIB + k] > 0.f) ? 1.f : 0.f;
            float d  = 1.f - (2.f * wsb[WS_SINKI + k] + 1e-5f) /
                             (wsb[WS_SP + 4 + 7 * k] + wsb[WS_TGT + k] + 1e-5f);
            cnt += fl;
            sd  += d * fl;
        }
        const float sink = (cnt > 0.f) ? 0.1f * (sd / fmaxf(cnt, 1.f)) : 0.f;
        out[b * 3 + 0] = ce;
        out[b * 3 + 1] = dice;
        out[b * 3 + 2] = sink;
    }
}

extern "C" void kernel_launch(void* const* d_in, const int* in_sizes, int n_in,
                              void* d_out, int out_size, void* d_ws, size_t ws_size,
                              hipStream_t stream) {
    const float* images  = (const float*)d_in[0];
    const int*   targets = (const int*)d_in[1];
    const int*   masks   = (const int*)d_in[2];
    float* out = (float*)d_out;
    float* ws  = (float*)d_ws;

    // zero the partial-sum workspace (harness re-poisons it to 0xAA)
    hipMemsetAsync(d_ws, 0, 2 * WS_STRIDE * sizeof(float), stream);

    // out layout: loss (2*3) | cm (2*32*3) | pred (2*96^3) as floats
    voxel_kernel<<<dim3(2 * NB), dim3(TPB), 0, stream>>>(
        images, targets, masks, ws, out + 6 + 2 * NC * 3);
    finalize_kernel<<<dim3(2), dim3(64), 0, stream>>>(ws, masks, out);
}

// Round 3
// 367.783 us; speedup vs baseline: 1.8838x; 1.8838x over previous
//
#include <hip/hip_runtime.h>

#define NC 32
#define NVOX (96*96*96)
#define NB 384            // blocks per sample: 384*256*9 == NVOX exactly
#define TPB 256

// per-block workspace slot layout (floats)
#define WS_CE     0
#define WS_SP     32
#define WS_SPT    64
#define WS_SINKI  96
#define WS_SIB    100
#define WS_TGT    104
#define WS_HIST   128
#define SLOT_STRIDE 1152          // 128 + 1024
#define NSLOT     (2 * NB)        // 768
#define FINAL_OFF (NSLOT * SLOT_STRIDE)

__device__ __forceinline__ float wave_reduce(float v) {
    #pragma unroll
    for (int off = 32; off > 0; off >>= 1)
        v += __shfl_down(v, off, 64);
    return v;
}

__global__ __launch_bounds__(TPB) void voxel_kernel(
    const float* __restrict__ images,
    const int*   __restrict__ targets,
    const int*   __restrict__ masks,     // bools promoted to 4-byte on device
    float* __restrict__ ws,
    float* __restrict__ pred_out)
{
    const int slot = blockIdx.x;
    const int b    = slot & 1;          // interleave samples across XCDs
    const int blk  = slot >> 1;
    const int tid  = threadIdx.x;

    __shared__ float s_hist[NC * NC];
    __shared__ float s_spt[NC];
    __shared__ float s_mf[NC];
    __shared__ float s_red[45];         // block-level reduce: ce, sp[32], sinkI[4], sib[4], tgt[4]

    for (int i = tid; i < NC * NC; i += TPB) s_hist[i] = 0.f;
    if (tid < 45) s_red[tid] = 0.f;
    if (tid < NC) {
        s_spt[tid] = 0.f;
        s_mf[tid]  = (masks[b * NC + tid] != 0) ? 1.f : 0.f;
    }
    __syncthreads();

    const float* img  = images + (size_t)b * NC * NVOX;
    const int*   tgt  = targets + (size_t)b * NVOX;
    float*       pout = pred_out + (size_t)b * NVOX;
    float*       wsb  = ws + (size_t)slot * SLOT_STRIDE;

    float sp[NC];
    #pragma unroll
    for (int c = 0; c < NC; ++c) sp[c] = 0.f;
    float ce = 0.f;
    float sinkI[4] = {0.f, 0.f, 0.f, 0.f};
    float sibc[4]  = {0.f, 0.f, 0.f, 0.f};
    float tgtc[4]  = {0.f, 0.f, 0.f, 0.f};

    for (int v = blk * TPB + tid; v < NVOX; v += NB * TPB) {
        const int  y     = tgt[v];
        const bool valid = (y != 255);
        const int  ysafe = valid ? y : 0;
        const float vwf  = valid ? 1.f : 0.f;

        // load 32 channels; argmax over RAW x for leaves (first-max, strict >)
        float e[NC];
        float sum  = 0.f;
        float best = -3.4e38f;
        int   pred = 4;
        #pragma unroll
        for (int c = 0; c < NC; ++c) {
            float x  = img[(size_t)c * NVOX + v];
            float ev = __expf(x);
            e[c] = ev;
            sum += ev;
            if (c >= 4 && x > best) { best = x; pred = c; }
        }
        const float rinv = 1.f / sum;
        pout[v] = (float)pred;

        const int pp = (pred - 4) / 7;                      // parent of pred, 0..3
        const int py = (ysafe >= 4) ? (ysafe - 4) / 7 : -1; // parent of y or -1

        // per-class prob sums + select p[y], p[parent(y)]
        float pyv = 0.f, ppv = 0.f;
        #pragma unroll
        for (int c = 0; c < NC; ++c) {
            float pc = e[c] * rinv;
            sp[c] += pc * vwf;
            if (c == ysafe) pyv = pc;
            if (c == py)    ppv = pc;
        }

        // CE: -(logp[y]*mf[y] + logp[py]*mf[py]) * vw
        float term = __logf(fminf(fmaxf(pyv, 1e-7f), 1.f - 1e-7f)) * s_mf[ysafe];
        if (py >= 0)
            term += __logf(fminf(fmaxf(ppv, 1e-7f), 1.f - 1e-7f)) * s_mf[py];
        ce -= term * vwf;

        // dice intersection terms (t-set = {y} ∪ {parent(y)})
        atomicAdd(&s_spt[ysafe], pyv * vwf);
        if (py >= 0) atomicAdd(&s_spt[py], ppv * vwf);

        // joint histogram hist[pred, y]
        atomicAdd(&s_hist[pred * NC + ysafe], vwf);

        // sink accounting
        const bool predMasked = (s_mf[pred] == 0.f);
        #pragma unroll
        for (int k = 0; k < 4; ++k) {
            const int  sk   = 4 + 7 * k;
            const bool ysib = (py == k) && (ysafe != sk);
            const bool msib = predMasked && (pp == k) && (pred != sk);
            const bool sib  = ysib || msib;
            if (sib && valid) sibc[k] += 1.f;
            const bool tg = (pp == k) && !sib && valid;
            if (tg) {
                tgtc[k]  += 1.f;
                sinkI[k] += e[sk] * rinv;
            }
        }
    }

    // wave reduce -> 4 LDS atomics per value (one per wave) -> private slot stores
    const int lane = tid & 63;
    {
        float r = wave_reduce(ce);
        if (lane == 0) atomicAdd(&s_red[0], r);
    }
    #pragma unroll
    for (int c = 0; c < NC; ++c) {
        float r = wave_reduce(sp[c]);
        if (lane == 0) atomicAdd(&s_red[1 + c], r);
    }
    #pragma unroll
    for (int k = 0; k < 4; ++k) {
        float r = wave_reduce(sinkI[k]);
        if (lane == 0) atomicAdd(&s_red[33 + k], r);
        r = wave_reduce(sibc[k]);
        if (lane == 0) atomicAdd(&s_red[37 + k], r);
        r = wave_reduce(tgtc[k]);
        if (lane == 0) atomicAdd(&s_red[41 + k], r);
    }
    __syncthreads();

    // plain coalesced stores to this block's private slot — zero global atomics
    for (int i = tid; i < NC * NC; i += TPB) wsb[WS_HIST + i] = s_hist[i];
    if (tid == 0) wsb[WS_CE] = s_red[0];
    if (tid < NC) {
        wsb[WS_SP  + tid] = s_red[1 + tid];
        wsb[WS_SPT + tid] = s_spt[tid];
    }
    if (tid < 4) {
        wsb[WS_SINKI + tid] = s_red[33 + tid];
        wsb[WS_SIB   + tid] = s_red[37 + tid];
        wsb[WS_TGT   + tid] = s_red[41 + tid];
    }
}

// sum 384 per-block slots per sample into the final region (coalesced)
__global__ __launch_bounds__(TPB) void reduce_kernel(
    const float* __restrict__ ws, float* __restrict__ wsf)
{
    const int g = blockIdx.x * TPB + threadIdx.x;
    if (g >= 2 * SLOT_STRIDE) return;
    const int b   = g / SLOT_STRIDE;
    const int val = g % SLOT_STRIDE;
    float s = 0.f;
    for (int blk = 0; blk < NB; ++blk)
        s += ws[(size_t)(2 * blk + b) * SLOT_STRIDE + val];
    wsf[(size_t)b * SLOT_STRIDE + val] = s;
}

__global__ __launch_bounds__(64) void finalize_kernel(
    const float* __restrict__ wsf,
    const int*   __restrict__ masks,
    float* __restrict__ out)
{
    const int b = blockIdx.x;
    const float* wsb  = wsf + (size_t)b * SLOT_STRIDE;
    const float* hist = wsb + WS_HIST;
    const int tid = threadIdx.x;

    __shared__ float s_col[NC], s_row[NC], s_dice[NC], s_mf[NC];

    if (tid < NC) {
        float cs = 0.f, rs = 0.f;
        for (int j = 0; j < NC; ++j) {
            cs += hist[j * NC + tid];
            rs += hist[tid * NC + j];
        }
        s_col[tid] = cs;
        s_row[tid] = rs;
        s_mf[tid]  = (masks[b * NC + tid] != 0) ? 1.f : 0.f;
    }
    __syncthreads();

    if (tid < NC) {
        const int c = tid;
        float ycnt, pcnt, tp;
        if (c < 4) {
            int idx[8];
            idx[0] = c;
            for (int j = 0; j < 7; ++j) idx[1 + j] = 4 + 7 * c + j;
            ycnt = s_col[c]; pcnt = s_row[c];
            for (int j = 0; j < 7; ++j) { ycnt += s_col[idx[1 + j]]; pcnt += s_row[idx[1 + j]]; }
            tp = 0.f;
            for (int a = 0; a < 8; ++a)
                for (int d = 0; d < 8; ++d)
                    tp += hist[idx[a] * NC + idx[d]];
        } else {
            ycnt = s_col[c]; pcnt = s_row[c];
            tp = hist[c * NC + c];
        }
        const float mf = s_mf[c];
        out[6 + (b * NC + c) * 3 + 0] = tp * mf;
        out[6 + (b * NC + c) * 3 + 1] = (pcnt - tp) * mf;
        out[6 + (b * NC + c) * 3 + 2] = (ycnt - tp) * mf;
        float dc = 1.f - 2.f * wsb[WS_SPT + c] / (wsb[WS_SP + c] + ycnt + 1e-5f);
        s_dice[c] = dc * mf;
    }
    __syncthreads();

    if (tid == 0) {
        float vw = 0.f, dsum = 0.f, msum = 0.f;
        for (int c = 0; c < NC; ++c) {
            vw   += s_col[c];
            dsum += s_dice[c];
            msum += s_mf[c];
        }
        const float ce   = wsb[WS_CE] / fmaxf(vw, 1.f);
        const float dice = dsum / fmaxf(msum, 1.f);
        float cnt = 0.f, sd = 0.f;
        for (int k = 0; k < 4; ++k) {
            float fl = (wsb[WS_SIB + k] > 0.f) ? 1.f : 0.f;
            float d  = 1.f - (2.f * wsb[WS_SINKI + k] + 1e-5f) /
                             (wsb[WS_SP + 4 + 7 * k] + wsb[WS_TGT + k] + 1e-5f);
            cnt += fl;
            sd  += d * fl;
        }
        const float sink = (cnt > 0.f) ? 0.1f * (sd / fmaxf(cnt, 1.f)) : 0.f;
        out[b * 3 + 0] = ce;
        out[b * 3 + 1] = dice;
        out[b * 3 + 2] = sink;
    }
}

extern "C" void kernel_launch(void* const* d_in, const int* in_sizes, int n_in,
                              void* d_out, int out_size, void* d_ws, size_t ws_size,
                              hipStream_t stream) {
    const float* images  = (const float*)d_in[0];
    const int*   targets = (const int*)d_in[1];
    const int*   masks   = (const int*)d_in[2];
    float* out = (float*)d_out;
    float* ws  = (float*)d_ws;
    float* wsf = ws + FINAL_OFF;

    // out layout: loss (2*3) | cm (2*32*3) | pred (2*96^3) as floats
    voxel_kernel<<<dim3(NSLOT), dim3(TPB), 0, stream>>>(
        images, targets, masks, ws, out + 6 + 2 * NC * 3);
    reduce_kernel<<<dim3((2 * SLOT_STRIDE + TPB - 1) / TPB), dim3(TPB), 0, stream>>>(ws, wsf);
    finalize_kernel<<<dim3(2), dim3(64), 0, stream>>>(wsf, masks, out);
}